// Round 4
// baseline (611.177 us; speedup 1.0000x reference)
//
#include <hip/hip_runtime.h>
#include <cstddef>
#include <cstdint>

#define HEADS 4
#define OUTC  40
#define NEG   0.2f
#define EPSV  1e-16f

typedef __bf16 bf16x8 __attribute__((ext_vector_type(8)));
typedef float  floatx4 __attribute__((ext_vector_type(4)));

__device__ __forceinline__ void split_bf16(float a, unsigned& hi, unsigned& lo) {
  unsigned u = __float_as_uint(a);
  hi = u >> 16;                                   // RTZ high bf16
  float hf = __uint_as_float(u & 0xFFFF0000u);
  lo = __float_as_uint(a - hf) >> 16;             // RTZ residual bf16
}

// ---------------- CSR build ----------------
__global__ void hist_k(const int* __restrict__ dst, int* __restrict__ cnt, int E) {
  int e = blockIdx.x * blockDim.x + threadIdx.x;
  if (e < E) atomicAdd(&cnt[dst[e]], 1);
}

__global__ __launch_bounds__(1024) void scanA_k(const int* __restrict__ cnt,
                                                int* __restrict__ rp,
                                                int* __restrict__ bsum, int n) {
  __shared__ int sh[1024];
  int i = blockIdx.x * 1024 + threadIdx.x;
  int v = (i < n) ? cnt[i] : 0;
  sh[threadIdx.x] = v;
  __syncthreads();
  for (int d = 1; d < 1024; d <<= 1) {
    int t = (threadIdx.x >= d) ? sh[threadIdx.x - d] : 0;
    __syncthreads();
    sh[threadIdx.x] += t;
    __syncthreads();
  }
  if (i < n) rp[i] = sh[threadIdx.x] - v;  // block-local exclusive
  if (threadIdx.x == 1023) bsum[blockIdx.x] = sh[1023];
}

__global__ void scanB_k(const int* __restrict__ bsum, int* __restrict__ boff, int nb) {
  if (blockIdx.x == 0 && threadIdx.x == 0) {
    int run = 0;
    for (int b = 0; b < nb; ++b) { boff[b] = run; run += bsum[b]; }
    boff[nb] = run;
  }
}

__global__ void scanC_k(int* __restrict__ rp, const int* __restrict__ boff, int n) {
  int i = blockIdx.x * blockDim.x + threadIdx.x;
  if (i < n) rp[i] += boff[i >> 10];
  if (i == 0) rp[n] = boff[(n + 1023) >> 10];
}

__global__ void scatter_k(const int* __restrict__ src, const int* __restrict__ dst,
                          const int* __restrict__ rp, int* __restrict__ cur,
                          int* __restrict__ out, int E) {
  int e = blockIdx.x * blockDim.x + threadIdx.x;
  if (e < E) {
    int d = dst[e];
    int p = rp[d] + atomicAdd(&cur[d], 1);
    out[p] = src[e];
  }
}

// ---------------- weight pre-split: W [K,Nc] fp32 -> Wh/Wl [256][K] bf16 ----------------
__global__ void convW1_k(const float* __restrict__ W, unsigned short* __restrict__ Wh,
                         unsigned short* __restrict__ Wl) {
  int id = blockIdx.x * 256 + threadIdx.x;  // 256*512
  int n = id >> 9, k = id & 511;
  unsigned h, l;
  split_bf16(W[k * 256 + n], h, l);
  Wh[id] = (unsigned short)h;
  Wl[id] = (unsigned short)l;
}

__global__ void convW2_k(const float* __restrict__ W, unsigned short* __restrict__ Wh,
                         unsigned short* __restrict__ Wl) {
  int id = blockIdx.x * 256 + threadIdx.x;  // 256*256, cols padded 160->256 per 64-group
  int n = id >> 8, k = id & 255;
  int hh = n >> 6, c = n & 63;
  float a = (c < OUTC) ? W[k * 160 + hh * OUTC + c] : 0.f;
  unsigned h, l;
  split_bf16(a, h, l);
  Wh[id] = (unsigned short)h;
  Wl[id] = (unsigned short)l;
}

// ---------------- split-bf16 MFMA GEMM, register-prefetch pipelined ----------------
// C[M,256] = A[M,K] @ B[K,256]. A fp32 (split in-kernel), B pre-split [n][K] bf16.
// Tile 64x128, BK=32, 4 waves (each 32x64). COMPACT: store only cols (g&63)<40
// compacted to [M,160].
// NOTE (R3 lesson): __launch_bounds__(256,4) capped unified VGPR+AGPR at 128/wave
// -> ~50 regs scratch-spilled -> WRITE_SIZE 332MB (6.5x C) and 205us. Do NOT
// force a min-occupancy here; register demand is ~180 regs.
template <bool COMPACT>
__global__ __launch_bounds__(256) void gemm_split(const float* __restrict__ A,
                                                  const unsigned short* __restrict__ Bh,
                                                  const unsigned short* __restrict__ Bl,
                                                  float* __restrict__ C, int M, int K) {
  __shared__ unsigned short Ah[64][40], Al[64][40], Bhs[128][40], Bls[128][40];
  const int tid = threadIdx.x;
  const int lane = tid & 63;
  const int w = tid >> 6;
  const int wr = w >> 1, wc = w & 1;
  const int row0 = blockIdx.y * 64;
  const int col0 = blockIdx.x * 128;
  const int fr = lane & 15, fq = lane >> 4;

  // staging indices (invariant)
  const int am = tid >> 3, aks = tid & 7;  // A: rows am, am+32; 4 floats at k = aks*4
  const int bn = tid >> 2, bg = tid & 3;   // B: rows bn, bn+64; 8 ushorts at k = bg*8

  floatx4 acc[2][4];
#pragma unroll
  for (int i = 0; i < 2; ++i)
#pragma unroll
    for (int j = 0; j < 4; ++j) acc[i][j] = (floatx4){0.f, 0.f, 0.f, 0.f};

  float4 pa[2];
  uint4 pbh[2], pbl[2];
  const float4 f4z = make_float4(0.f, 0.f, 0.f, 0.f);

#define PREF(K0)                                                                      \
  do {                                                                                \
    int gr0 = row0 + am, gr1 = row0 + am + 32;                                        \
    pa[0] = (gr0 < M) ? *(const float4*)&A[(size_t)gr0 * K + (K0) + aks * 4] : f4z;   \
    pa[1] = (gr1 < M) ? *(const float4*)&A[(size_t)gr1 * K + (K0) + aks * 4] : f4z;   \
    size_t gb0 = (size_t)(col0 + bn) * K + (K0) + bg * 8;                             \
    size_t gb1 = (size_t)(col0 + bn + 64) * K + (K0) + bg * 8;                        \
    pbh[0] = *(const uint4*)&Bh[gb0];                                                 \
    pbl[0] = *(const uint4*)&Bl[gb0];                                                 \
    pbh[1] = *(const uint4*)&Bh[gb1];                                                 \
    pbl[1] = *(const uint4*)&Bl[gb1];                                                 \
  } while (0)

  PREF(0);
  int k0 = 0;
  while (true) {
    // commit prefetched regs -> LDS (vmcnt wait lands here)
#pragma unroll
    for (int t = 0; t < 2; ++t) {
      unsigned h0, l0, h1, l1, h2, l2, h3, l3;
      split_bf16(pa[t].x, h0, l0);
      split_bf16(pa[t].y, h1, l1);
      split_bf16(pa[t].z, h2, l2);
      split_bf16(pa[t].w, h3, l3);
      *(uint2*)&Ah[am + 32 * t][aks * 4] = make_uint2(h0 | (h1 << 16), h2 | (h3 << 16));
      *(uint2*)&Al[am + 32 * t][aks * 4] = make_uint2(l0 | (l1 << 16), l2 | (l3 << 16));
      *(uint4*)&Bhs[bn + 64 * t][bg * 8] = pbh[t];
      *(uint4*)&Bls[bn + 64 * t][bg * 8] = pbl[t];
    }
    __syncthreads();
    const int kn = k0 + 32;
    if (kn < K) PREF(kn);  // issue next tile's loads; consumed next commit

    bf16x8 ah[2], al[2], bh[4], bl[4];
#pragma unroll
    for (int i = 0; i < 2; ++i) {
      ah[i] = *(bf16x8*)&Ah[wr * 32 + i * 16 + fr][fq * 8];
      al[i] = *(bf16x8*)&Al[wr * 32 + i * 16 + fr][fq * 8];
    }
#pragma unroll
    for (int j = 0; j < 4; ++j) {
      bh[j] = *(bf16x8*)&Bhs[wc * 64 + j * 16 + fr][fq * 8];
      bl[j] = *(bf16x8*)&Bls[wc * 64 + j * 16 + fr][fq * 8];
    }
#pragma unroll
    for (int i = 0; i < 2; ++i)
#pragma unroll
      for (int j = 0; j < 4; ++j) {
        acc[i][j] = __builtin_amdgcn_mfma_f32_16x16x32_bf16(ah[i], bh[j], acc[i][j], 0, 0, 0);
        acc[i][j] = __builtin_amdgcn_mfma_f32_16x16x32_bf16(ah[i], bl[j], acc[i][j], 0, 0, 0);
        acc[i][j] = __builtin_amdgcn_mfma_f32_16x16x32_bf16(al[i], bh[j], acc[i][j], 0, 0, 0);
      }
    k0 = kn;
    if (k0 >= K) break;
    __syncthreads();
  }
#undef PREF

  // epilogue: C/D layout col=lane&15, row=(lane>>4)*4+r  [m89]
#pragma unroll
  for (int i = 0; i < 2; ++i) {
    int grow_base = row0 + wr * 32 + i * 16 + fq * 4;
#pragma unroll
    for (int r = 0; r < 4; ++r) {
      int grow = grow_base + r;
      if (grow < M) {
        if (COMPACT) {
          int head = blockIdx.x * 2 + wc;
#pragma unroll
          for (int j = 0; j < 4; ++j) {
            int cc = j * 16 + fr;
            if (cc < OUTC) C[(size_t)grow * 160 + head * OUTC + cc] = acc[i][j][r];
          }
        } else {
#pragma unroll
          for (int j = 0; j < 4; ++j)
            C[(size_t)grow * 256 + col0 + wc * 64 + j * 16 + fr] = acc[i][j][r];
        }
      }
    }
  }
}

// ---------------- layer-1 agg: wave per node, lane = (head, 4 channels) ----------------
__global__ __launch_bounds__(256) void agg1_k(const float* __restrict__ h,
                                              const int* __restrict__ rp,
                                              const int* __restrict__ srt,
                                              const float* __restrict__ b1,
                                              float* __restrict__ out, int Nn) {
  int wv = threadIdx.x >> 6, lane = threadIdx.x & 63;
  int node = blockIdx.x * 4 + wv;
  if (node >= Nn) node = Nn - 1;
  const float4 xi = *(const float4*)&h[(size_t)node * 256 + lane * 4];
  float p = xi.x * xi.x + xi.y * xi.y + xi.z * xi.z + xi.w * xi.w;
  p += __shfl_xor(p, 1); p += __shfl_xor(p, 2); p += __shfl_xor(p, 4); p += __shfl_xor(p, 8);
  float a = p > 0.f ? p : NEG * p;      // self-loop logit
  float m = a, l = 1.f;
  float4 acc = xi;
  const int e0 = rp[node], e1 = rp[node + 1];
  for (int e = e0; e < e1; ++e) {
    int s = srt[e];
    const float4 xj = *(const float4*)&h[(size_t)s * 256 + lane * 4];
    float q = xi.x * xj.x + xi.y * xj.y + xi.z * xj.z + xi.w * xj.w;
    q += __shfl_xor(q, 1); q += __shfl_xor(q, 2); q += __shfl_xor(q, 4); q += __shfl_xor(q, 8);
    float al = q > 0.f ? q : NEG * q;
    float nm = fmaxf(m, al);
    float sc = __expf(m - nm), wt = __expf(al - nm);
    l = l * sc + wt;
    acc.x = acc.x * sc + wt * xj.x;
    acc.y = acc.y * sc + wt * xj.y;
    acc.z = acc.z * sc + wt * xj.z;
    acc.w = acc.w * sc + wt * xj.w;
    m = nm;
  }
  float inv = 1.f / (l + EPSV);
  const float4 bb = *(const float4*)&b1[lane * 4];
  float4 o;
  o.x = acc.x * inv + bb.x;
  o.y = acc.y * inv + bb.y;
  o.z = acc.z * inv + bb.z;
  o.w = acc.w * inv + bb.w;
  o.x = o.x > 0.f ? o.x : __expf(o.x) - 1.f;
  o.y = o.y > 0.f ? o.y : __expf(o.y) - 1.f;
  o.z = o.z > 0.f ? o.z : __expf(o.z) - 1.f;
  o.w = o.w > 0.f ? o.w : __expf(o.w) - 1.f;
  *(float4*)&out[(size_t)node * 256 + lane * 4] = o;
}

// ---------------- layer-2 agg (compact [N,160] input) + head-mean + log_softmax ----------------
__global__ __launch_bounds__(256) void agg2_k(const float* __restrict__ h,
                                              const int* __restrict__ rp,
                                              const int* __restrict__ srt,
                                              const float* __restrict__ b2,
                                              float* __restrict__ out, int Nn) {
  __shared__ float buf[4][160];
  int wv = threadIdx.x >> 6, lane = threadIdx.x & 63;
  int node = blockIdx.x * 4 + wv;
  if (node >= Nn) node = Nn - 1;
  const int head = lane >> 4, c4 = lane & 15;
  const bool act = c4 < 10;  // 10 lanes x float4 = 40 channels per head
  float4 xi = make_float4(0.f, 0.f, 0.f, 0.f);
  if (act) xi = *(const float4*)&h[(size_t)node * 160 + head * OUTC + c4 * 4];
  float p = xi.x * xi.x + xi.y * xi.y + xi.z * xi.z + xi.w * xi.w;
  p += __shfl_xor(p, 1); p += __shfl_xor(p, 2); p += __shfl_xor(p, 4); p += __shfl_xor(p, 8);
  float a = p > 0.f ? p : NEG * p;
  float m = a, l = 1.f;
  float4 acc = xi;
  const int e0 = rp[node], e1 = rp[node + 1];
  for (int e = e0; e < e1; ++e) {
    int s = srt[e];
    float4 xj = make_float4(0.f, 0.f, 0.f, 0.f);
    if (act) xj = *(const float4*)&h[(size_t)s * 160 + head * OUTC + c4 * 4];
    float q = xi.x * xj.x + xi.y * xj.y + xi.z * xj.z + xi.w * xj.w;
    q += __shfl_xor(q, 1); q += __shfl_xor(q, 2); q += __shfl_xor(q, 4); q += __shfl_xor(q, 8);
    float al = q > 0.f ? q : NEG * q;
    float nm = fmaxf(m, al);
    float sc = __expf(m - nm), wt = __expf(al - nm);
    l = l * sc + wt;
    acc.x = acc.x * sc + wt * xj.x;
    acc.y = acc.y * sc + wt * xj.y;
    acc.z = acc.z * sc + wt * xj.z;
    acc.w = acc.w * sc + wt * xj.w;
    m = nm;
  }
  float inv = 1.f / (l + EPSV);
  if (act) {
    float4 res;
    res.x = acc.x * inv; res.y = acc.y * inv; res.z = acc.z * inv; res.w = acc.w * inv;
    *(float4*)&buf[wv][head * OUTC + c4 * 4] = res;
  }
  __syncthreads();
  const bool valid = lane < OUTC;
  float v = 0.f;
  if (valid)
    v = 0.25f * (buf[wv][lane] + buf[wv][OUTC + lane] + buf[wv][2 * OUTC + lane] +
                 buf[wv][3 * OUTC + lane]) + b2[lane];
  float t = valid ? v : -1e30f;
#pragma unroll
  for (int off = 32; off; off >>= 1) t = fmaxf(t, __shfl_xor(t, off));
  float ex = valid ? __expf(v - t) : 0.f;
  float s = ex;
#pragma unroll
  for (int off = 32; off; off >>= 1) s += __shfl_xor(s, off);
  float lse = t + __logf(s);
  if (valid) out[(size_t)node * OUTC + lane] = v - lse;
  if (blockIdx.x == 0 && threadIdx.x == 0) out[(size_t)Nn * OUTC] = 0.f;  // att_loss
}

extern "C" void kernel_launch(void* const* d_in, const int* in_sizes, int n_in,
                              void* d_out, int out_size, void* d_ws, size_t ws_size,
                              hipStream_t stream) {
  const float* x  = (const float*)d_in[0];
  const int*   ei = (const int*)d_in[1];
  const float* W1 = (const float*)d_in[2];
  const float* b1 = (const float*)d_in[3];
  const float* W2 = (const float*)d_in[4];
  const float* b2 = (const float*)d_in[5];
  float* out = (float*)d_out;

  const int Nn = in_sizes[0] / 512;  // 50000
  const int E  = in_sizes[1] / 2;    // 400000
  const int* esrc = ei;
  const int* edst = ei + E;
  const int NB = (Nn + 1023) / 1024;

  // workspace layout
  char* ws = (char*)d_ws;
  const size_t szH = (size_t)Nn * 256 * sizeof(float);  // 51.2 MB
  float* h1 = (float*)(ws);           // GEMM1 out [N,256]; reused as h2 [N,160]
  float* g1 = (float*)(ws + szH);     // layer-1 activations [N,256]
  size_t off = 2 * szH;
  int* rp = (int*)(ws + off);   off += ((size_t)(Nn + 1) * 4 + 15) & ~(size_t)15;
  int* cnt = (int*)(ws + off);  off += ((size_t)Nn * 4 + 15) & ~(size_t)15;
  int* srt = (int*)(ws + off);  off += ((size_t)E * 4 + 15) & ~(size_t)15;
  int* bsum = (int*)(ws + off); off += 1024;
  int* boff = (int*)(ws + off); off += 1024;
  unsigned short* Wh1 = (unsigned short*)(ws + off); off += (size_t)256 * 512 * 2;
  unsigned short* Wl1 = (unsigned short*)(ws + off); off += (size_t)256 * 512 * 2;
  unsigned short* Wh2 = (unsigned short*)(ws + off); off += (size_t)256 * 256 * 2;
  unsigned short* Wl2 = (unsigned short*)(ws + off); off += (size_t)256 * 256 * 2;
  float* h2 = h1;

  // CSR by destination
  hipMemsetAsync(cnt, 0, (size_t)Nn * sizeof(int), stream);
  hist_k<<<(E + 255) / 256, 256, 0, stream>>>(edst, cnt, E);
  scanA_k<<<NB, 1024, 0, stream>>>(cnt, rp, bsum, Nn);
  scanB_k<<<1, 64, 0, stream>>>(bsum, boff, NB);
  scanC_k<<<(Nn + 255) / 256, 256, 0, stream>>>(rp, boff, Nn);
  hipMemsetAsync(cnt, 0, (size_t)Nn * sizeof(int), stream);
  scatter_k<<<(E + 255) / 256, 256, 0, stream>>>(esrc, edst, rp, cnt, srt, E);

  // weight pre-split
  convW1_k<<<512, 256, 0, stream>>>(W1, Wh1, Wl1);
  convW2_k<<<256, 256, 0, stream>>>(W2, Wh2, Wl2);

  // layer 1
  gemm_split<false>
      <<<dim3(2, (Nn + 63) / 64), 256, 0, stream>>>(x, Wh1, Wl1, h1, Nn, 512);
  agg1_k<<<(Nn + 3) / 4, 256, 0, stream>>>(h1, rp, srt, b1, g1, Nn);

  // layer 2 (compact [N,160] intermediate)
  gemm_split<true>
      <<<dim3(2, (Nn + 63) / 64), 256, 0, stream>>>(g1, Wh2, Wl2, h2, Nn, 256);
  agg2_k<<<(Nn + 3) / 4, 256, 0, stream>>>(h2, rp, srt, b2, out, Nn);
}

// Round 5
// 567.863 us; speedup vs baseline: 1.0763x; 1.0763x over previous
//
#include <hip/hip_runtime.h>
#include <cstddef>
#include <cstdint>

#define HEADS 4
#define OUTC  40
#define NEG   0.2f
#define EPSV  1e-16f

typedef __bf16 bf16x8 __attribute__((ext_vector_type(8)));
typedef float  floatx4 __attribute__((ext_vector_type(4)));

__device__ __forceinline__ void split_bf16(float a, unsigned& hi, unsigned& lo) {
  unsigned u = __float_as_uint(a);
  hi = u >> 16;                                   // RTZ high bf16
  float hf = __uint_as_float(u & 0xFFFF0000u);
  lo = __float_as_uint(a - hf) >> 16;             // RTZ residual bf16
}

// ---------------- CSR build ----------------
__global__ void hist_k(const int* __restrict__ dst, int* __restrict__ cnt, int E) {
  int e = blockIdx.x * blockDim.x + threadIdx.x;
  if (e < E) atomicAdd(&cnt[dst[e]], 1);
}

__global__ __launch_bounds__(1024) void scanA_k(const int* __restrict__ cnt,
                                                int* __restrict__ rp,
                                                int* __restrict__ bsum, int n) {
  __shared__ int sh[1024];
  int i = blockIdx.x * 1024 + threadIdx.x;
  int v = (i < n) ? cnt[i] : 0;
  sh[threadIdx.x] = v;
  __syncthreads();
  for (int d = 1; d < 1024; d <<= 1) {
    int t = (threadIdx.x >= d) ? sh[threadIdx.x - d] : 0;
    __syncthreads();
    sh[threadIdx.x] += t;
    __syncthreads();
  }
  if (i < n) rp[i] = sh[threadIdx.x] - v;  // block-local exclusive
  if (threadIdx.x == 1023) bsum[blockIdx.x] = sh[1023];
}

__global__ void scanB_k(const int* __restrict__ bsum, int* __restrict__ boff, int nb) {
  if (blockIdx.x == 0 && threadIdx.x == 0) {
    int run = 0;
    for (int b = 0; b < nb; ++b) { boff[b] = run; run += bsum[b]; }
    boff[nb] = run;
  }
}

__global__ void scanC_k(int* __restrict__ rp, const int* __restrict__ boff, int n) {
  int i = blockIdx.x * blockDim.x + threadIdx.x;
  if (i < n) rp[i] += boff[i >> 10];
  if (i == 0) rp[n] = boff[(n + 1023) >> 10];
}

__global__ void scatter_k(const int* __restrict__ src, const int* __restrict__ dst,
                          const int* __restrict__ rp, int* __restrict__ cur,
                          int* __restrict__ out, int E) {
  int e = blockIdx.x * blockDim.x + threadIdx.x;
  if (e < E) {
    int d = dst[e];
    int p = rp[d] + atomicAdd(&cur[d], 1);
    out[p] = src[e];
  }
}

// ---------------- weight pre-split: W [K,Nc] fp32 -> Wh/Wl [256][K] bf16 ----------------
__global__ void convW1_k(const float* __restrict__ W, unsigned short* __restrict__ Wh,
                         unsigned short* __restrict__ Wl) {
  int id = blockIdx.x * 256 + threadIdx.x;  // 256*512
  int n = id >> 9, k = id & 511;
  unsigned h, l;
  split_bf16(W[k * 256 + n], h, l);
  Wh[id] = (unsigned short)h;
  Wl[id] = (unsigned short)l;
}

__global__ void convW2_k(const float* __restrict__ W, unsigned short* __restrict__ Wh,
                         unsigned short* __restrict__ Wl) {
  int id = blockIdx.x * 256 + threadIdx.x;  // 256*256, cols padded 160->256 per 64-group
  int n = id >> 8, k = id & 255;
  int hh = n >> 6, c = n & 63;
  float a = (c < OUTC) ? W[k * 160 + hh * OUTC + c] : 0.f;
  unsigned h, l;
  split_bf16(a, h, l);
  Wh[id] = (unsigned short)h;
  Wl[id] = (unsigned short)l;
}

// ---------------- split-bf16 MFMA GEMM, 128x128 tile, register-prefetch pipelined ----
// C[M,256] = A[M,K] @ B[K,256]. A fp32 (split in-kernel), B pre-split [n][K] bf16.
// BK=32, 4 waves in 2x2, each computes 64x64 (acc 4x4 of 16x16).
// REGISTER NOTE (R3/R4 lesson): the backend derives its register budget from
// LDS-implied occupancy (40KB -> 4 wg/CU -> 128 regs/wave) and SPILLS this
// kernel's ~210-reg demand to scratch (WRITE_SIZE 270-330MB vs 51MB ideal).
// __launch_bounds__(256, 2) grants a 256-reg budget: no spill, 2 wg/CU.
template <bool COMPACT>
__global__ __launch_bounds__(256, 2) void gemm_split(const float* __restrict__ A,
                                                     const unsigned short* __restrict__ Bh,
                                                     const unsigned short* __restrict__ Bl,
                                                     float* __restrict__ C, int M, int K) {
  __shared__ unsigned short Ah[128][40], Al[128][40], Bhs[128][40], Bls[128][40];
  const int tid = threadIdx.x;
  const int lane = tid & 63;
  const int w = tid >> 6;
  const int wr = w >> 1, wc = w & 1;
  const int row0 = blockIdx.y * 128;
  const int col0 = blockIdx.x * 128;
  const int fr = lane & 15, fq = lane >> 4;

  // staging indices (invariant)
  const int am = tid >> 3, aks = tid & 7;  // A: rows am+32t (t=0..3); 4 floats at k=aks*4
  const int bn = tid >> 2, bg = tid & 3;   // B: rows bn+64t (t=0..1); 8 ushorts at k=bg*8

  floatx4 acc[4][4];
#pragma unroll
  for (int i = 0; i < 4; ++i)
#pragma unroll
    for (int j = 0; j < 4; ++j) acc[i][j] = (floatx4){0.f, 0.f, 0.f, 0.f};

  float4 pa[4];
  uint4 pbh[2], pbl[2];
  const float4 f4z = make_float4(0.f, 0.f, 0.f, 0.f);

#define PREF(K0)                                                                      \
  do {                                                                                \
    _Pragma("unroll") for (int t = 0; t < 4; ++t) {                                   \
      int gr = row0 + am + 32 * t;                                                    \
      pa[t] = (gr < M) ? *(const float4*)&A[(size_t)gr * K + (K0) + aks * 4] : f4z;   \
    }                                                                                 \
    _Pragma("unroll") for (int t = 0; t < 2; ++t) {                                   \
      size_t gb = (size_t)(col0 + bn + 64 * t) * K + (K0) + bg * 8;                   \
      pbh[t] = *(const uint4*)&Bh[gb];                                                \
      pbl[t] = *(const uint4*)&Bl[gb];                                                \
    }                                                                                 \
  } while (0)

  PREF(0);
  int k0 = 0;
  while (true) {
    // commit prefetched regs -> LDS (vmcnt wait lands here)
#pragma unroll
    for (int t = 0; t < 4; ++t) {
      unsigned h0, l0, h1, l1, h2, l2, h3, l3;
      split_bf16(pa[t].x, h0, l0);
      split_bf16(pa[t].y, h1, l1);
      split_bf16(pa[t].z, h2, l2);
      split_bf16(pa[t].w, h3, l3);
      *(uint2*)&Ah[am + 32 * t][aks * 4] = make_uint2(h0 | (h1 << 16), h2 | (h3 << 16));
      *(uint2*)&Al[am + 32 * t][aks * 4] = make_uint2(l0 | (l1 << 16), l2 | (l3 << 16));
    }
#pragma unroll
    for (int t = 0; t < 2; ++t) {
      *(uint4*)&Bhs[bn + 64 * t][bg * 8] = pbh[t];
      *(uint4*)&Bls[bn + 64 * t][bg * 8] = pbl[t];
    }
    __syncthreads();
    const int kn = k0 + 32;
    if (kn < K) PREF(kn);  // issue next tile's loads; consumed at next commit

    bf16x8 ah[4], al[4], bh[4], bl[4];
#pragma unroll
    for (int i = 0; i < 4; ++i) {
      ah[i] = *(bf16x8*)&Ah[wr * 64 + i * 16 + fr][fq * 8];
      al[i] = *(bf16x8*)&Al[wr * 64 + i * 16 + fr][fq * 8];
      bh[i] = *(bf16x8*)&Bhs[wc * 64 + i * 16 + fr][fq * 8];
      bl[i] = *(bf16x8*)&Bls[wc * 64 + i * 16 + fr][fq * 8];
    }
#pragma unroll
    for (int i = 0; i < 4; ++i)
#pragma unroll
      for (int j = 0; j < 4; ++j) {
        acc[i][j] = __builtin_amdgcn_mfma_f32_16x16x32_bf16(ah[i], bh[j], acc[i][j], 0, 0, 0);
        acc[i][j] = __builtin_amdgcn_mfma_f32_16x16x32_bf16(ah[i], bl[j], acc[i][j], 0, 0, 0);
        acc[i][j] = __builtin_amdgcn_mfma_f32_16x16x32_bf16(al[i], bh[j], acc[i][j], 0, 0, 0);
      }
    k0 = kn;
    if (k0 >= K) break;
    __syncthreads();
  }
#undef PREF

  // epilogue: C/D layout col=lane&15, row=(lane>>4)*4+r  [m89]
#pragma unroll
  for (int i = 0; i < 4; ++i) {
    int grow_base = row0 + wr * 64 + i * 16 + fq * 4;
#pragma unroll
    for (int r = 0; r < 4; ++r) {
      int grow = grow_base + r;
      if (grow < M) {
        if (COMPACT) {
          int head = blockIdx.x * 2 + wc;
#pragma unroll
          for (int j = 0; j < 4; ++j) {
            int cc = j * 16 + fr;
            if (cc < OUTC) C[(size_t)grow * 160 + head * OUTC + cc] = acc[i][j][r];
          }
        } else {
#pragma unroll
          for (int j = 0; j < 4; ++j)
            C[(size_t)grow * 256 + col0 + wc * 64 + j * 16 + fr] = acc[i][j][r];
        }
      }
    }
  }
}

// ---------------- layer-1 agg: wave per node, lane = (head, 4 channels) ----------------
__global__ __launch_bounds__(256) void agg1_k(const float* __restrict__ h,
                                              const int* __restrict__ rp,
                                              const int* __restrict__ srt,
                                              const float* __restrict__ b1,
                                              float* __restrict__ out, int Nn) {
  int wv = threadIdx.x >> 6, lane = threadIdx.x & 63;
  int node = blockIdx.x * 4 + wv;
  if (node >= Nn) node = Nn - 1;
  const float4 xi = *(const float4*)&h[(size_t)node * 256 + lane * 4];
  float p = xi.x * xi.x + xi.y * xi.y + xi.z * xi.z + xi.w * xi.w;
  p += __shfl_xor(p, 1); p += __shfl_xor(p, 2); p += __shfl_xor(p, 4); p += __shfl_xor(p, 8);
  float a = p > 0.f ? p : NEG * p;      // self-loop logit
  float m = a, l = 1.f;
  float4 acc = xi;
  const int e0 = rp[node], e1 = rp[node + 1];
  for (int e = e0; e < e1; ++e) {
    int s = srt[e];
    const float4 xj = *(const float4*)&h[(size_t)s * 256 + lane * 4];
    float q = xi.x * xj.x + xi.y * xj.y + xi.z * xj.z + xi.w * xj.w;
    q += __shfl_xor(q, 1); q += __shfl_xor(q, 2); q += __shfl_xor(q, 4); q += __shfl_xor(q, 8);
    float al = q > 0.f ? q : NEG * q;
    float nm = fmaxf(m, al);
    float sc = __expf(m - nm), wt = __expf(al - nm);
    l = l * sc + wt;
    acc.x = acc.x * sc + wt * xj.x;
    acc.y = acc.y * sc + wt * xj.y;
    acc.z = acc.z * sc + wt * xj.z;
    acc.w = acc.w * sc + wt * xj.w;
    m = nm;
  }
  float inv = 1.f / (l + EPSV);
  const float4 bb = *(const float4*)&b1[lane * 4];
  float4 o;
  o.x = acc.x * inv + bb.x;
  o.y = acc.y * inv + bb.y;
  o.z = acc.z * inv + bb.z;
  o.w = acc.w * inv + bb.w;
  o.x = o.x > 0.f ? o.x : __expf(o.x) - 1.f;
  o.y = o.y > 0.f ? o.y : __expf(o.y) - 1.f;
  o.z = o.z > 0.f ? o.z : __expf(o.z) - 1.f;
  o.w = o.w > 0.f ? o.w : __expf(o.w) - 1.f;
  *(float4*)&out[(size_t)node * 256 + lane * 4] = o;
}

// ---------------- layer-2 agg (compact [N,160] input) + head-mean + log_softmax ----------------
__global__ __launch_bounds__(256) void agg2_k(const float* __restrict__ h,
                                              const int* __restrict__ rp,
                                              const int* __restrict__ srt,
                                              const float* __restrict__ b2,
                                              float* __restrict__ out, int Nn) {
  __shared__ float buf[4][160];
  int wv = threadIdx.x >> 6, lane = threadIdx.x & 63;
  int node = blockIdx.x * 4 + wv;
  if (node >= Nn) node = Nn - 1;
  const int head = lane >> 4, c4 = lane & 15;
  const bool act = c4 < 10;  // 10 lanes x float4 = 40 channels per head
  float4 xi = make_float4(0.f, 0.f, 0.f, 0.f);
  if (act) xi = *(const float4*)&h[(size_t)node * 160 + head * OUTC + c4 * 4];
  float p = xi.x * xi.x + xi.y * xi.y + xi.z * xi.z + xi.w * xi.w;
  p += __shfl_xor(p, 1); p += __shfl_xor(p, 2); p += __shfl_xor(p, 4); p += __shfl_xor(p, 8);
  float a = p > 0.f ? p : NEG * p;
  float m = a, l = 1.f;
  float4 acc = xi;
  const int e0 = rp[node], e1 = rp[node + 1];
  for (int e = e0; e < e1; ++e) {
    int s = srt[e];
    float4 xj = make_float4(0.f, 0.f, 0.f, 0.f);
    if (act) xj = *(const float4*)&h[(size_t)s * 160 + head * OUTC + c4 * 4];
    float q = xi.x * xj.x + xi.y * xj.y + xi.z * xj.z + xi.w * xj.w;
    q += __shfl_xor(q, 1); q += __shfl_xor(q, 2); q += __shfl_xor(q, 4); q += __shfl_xor(q, 8);
    float al = q > 0.f ? q : NEG * q;
    float nm = fmaxf(m, al);
    float sc = __expf(m - nm), wt = __expf(al - nm);
    l = l * sc + wt;
    acc.x = acc.x * sc + wt * xj.x;
    acc.y = acc.y * sc + wt * xj.y;
    acc.z = acc.z * sc + wt * xj.z;
    acc.w = acc.w * sc + wt * xj.w;
    m = nm;
  }
  float inv = 1.f / (l + EPSV);
  if (act) {
    float4 res;
    res.x = acc.x * inv; res.y = acc.y * inv; res.z = acc.z * inv; res.w = acc.w * inv;
    *(float4*)&buf[wv][head * OUTC + c4 * 4] = res;
  }
  __syncthreads();
  const bool valid = lane < OUTC;
  float v = 0.f;
  if (valid)
    v = 0.25f * (buf[wv][lane] + buf[wv][OUTC + lane] + buf[wv][2 * OUTC + lane] +
                 buf[wv][3 * OUTC + lane]) + b2[lane];
  float t = valid ? v : -1e30f;
#pragma unroll
  for (int off = 32; off; off >>= 1) t = fmaxf(t, __shfl_xor(t, off));
  float ex = valid ? __expf(v - t) : 0.f;
  float s = ex;
#pragma unroll
  for (int off = 32; off; off >>= 1) s += __shfl_xor(s, off);
  float lse = t + __logf(s);
  if (valid) out[(size_t)node * OUTC + lane] = v - lse;
  if (blockIdx.x == 0 && threadIdx.x == 0) out[(size_t)Nn * OUTC] = 0.f;  // att_loss
}

extern "C" void kernel_launch(void* const* d_in, const int* in_sizes, int n_in,
                              void* d_out, int out_size, void* d_ws, size_t ws_size,
                              hipStream_t stream) {
  const float* x  = (const float*)d_in[0];
  const int*   ei = (const int*)d_in[1];
  const float* W1 = (const float*)d_in[2];
  const float* b1 = (const float*)d_in[3];
  const float* W2 = (const float*)d_in[4];
  const float* b2 = (const float*)d_in[5];
  float* out = (float*)d_out;

  const int Nn = in_sizes[0] / 512;  // 50000
  const int E  = in_sizes[1] / 2;    // 400000
  const int* esrc = ei;
  const int* edst = ei + E;
  const int NB = (Nn + 1023) / 1024;

  // workspace layout
  char* ws = (char*)d_ws;
  const size_t szH = (size_t)Nn * 256 * sizeof(float);  // 51.2 MB
  float* h1 = (float*)(ws);           // GEMM1 out [N,256]; reused as h2 [N,160]
  float* g1 = (float*)(ws + szH);     // layer-1 activations [N,256]
  size_t off = 2 * szH;
  int* rp = (int*)(ws + off);   off += ((size_t)(Nn + 1) * 4 + 15) & ~(size_t)15;
  int* cnt = (int*)(ws + off);  off += ((size_t)Nn * 4 + 15) & ~(size_t)15;
  int* srt = (int*)(ws + off);  off += ((size_t)E * 4 + 15) & ~(size_t)15;
  int* bsum = (int*)(ws + off); off += 1024;
  int* boff = (int*)(ws + off); off += 1024;
  unsigned short* Wh1 = (unsigned short*)(ws + off); off += (size_t)256 * 512 * 2;
  unsigned short* Wl1 = (unsigned short*)(ws + off); off += (size_t)256 * 512 * 2;
  unsigned short* Wh2 = (unsigned short*)(ws + off); off += (size_t)256 * 256 * 2;
  unsigned short* Wl2 = (unsigned short*)(ws + off); off += (size_t)256 * 256 * 2;
  float* h2 = h1;

  // CSR by destination
  hipMemsetAsync(cnt, 0, (size_t)Nn * sizeof(int), stream);
  hist_k<<<(E + 255) / 256, 256, 0, stream>>>(edst, cnt, E);
  scanA_k<<<NB, 1024, 0, stream>>>(cnt, rp, bsum, Nn);
  scanB_k<<<1, 64, 0, stream>>>(bsum, boff, NB);
  scanC_k<<<(Nn + 255) / 256, 256, 0, stream>>>(rp, boff, Nn);
  hipMemsetAsync(cnt, 0, (size_t)Nn * sizeof(int), stream);
  scatter_k<<<(E + 255) / 256, 256, 0, stream>>>(esrc, edst, rp, cnt, srt, E);

  // weight pre-split
  convW1_k<<<512, 256, 0, stream>>>(W1, Wh1, Wl1);
  convW2_k<<<256, 256, 0, stream>>>(W2, Wh2, Wl2);

  // layer 1
  gemm_split<false>
      <<<dim3(2, (Nn + 127) / 128), 256, 0, stream>>>(x, Wh1, Wl1, h1, Nn, 512);
  agg1_k<<<(Nn + 3) / 4, 256, 0, stream>>>(h1, rp, srt, b1, g1, Nn);

  // layer 2 (compact [N,160] intermediate)
  gemm_split<true>
      <<<dim3(2, (Nn + 127) / 128), 256, 0, stream>>>(g1, Wh2, Wl2, h2, Nn, 256);
  agg2_k<<<(Nn + 3) / 4, 256, 0, stream>>>(h2, rp, srt, b2, out, Nn);
}

// Round 6
// 445.943 us; speedup vs baseline: 1.3705x; 1.2734x over previous
//
#include <hip/hip_runtime.h>
#include <cstddef>
#include <cstdint>

#define HEADS 4
#define OUTC  40
#define NEG   0.2f
#define EPSV  1e-16f

typedef __bf16 bf16x8 __attribute__((ext_vector_type(8)));
typedef float  floatx4 __attribute__((ext_vector_type(4)));

__device__ __forceinline__ void split_bf16(float a, unsigned& hi, unsigned& lo) {
  unsigned u = __float_as_uint(a);
  hi = u >> 16;                                   // RTZ high bf16
  float hf = __uint_as_float(u & 0xFFFF0000u);
  lo = __float_as_uint(a - hf) >> 16;             // RTZ residual bf16
}

// async global->LDS DMA, 16B per lane. lds ptr must be wave-uniform base;
// HW writes lane i at base + i*16 (m97/m104).
__device__ __forceinline__ void dma16(const void* g, void* l) {
  __builtin_amdgcn_global_load_lds(
      (const __attribute__((address_space(1))) unsigned int*)g,
      (__attribute__((address_space(3))) unsigned int*)l, 16, 0, 0);
}

// ---------------- CSR build ----------------
__global__ void hist_k(const int* __restrict__ dst, int* __restrict__ cnt, int E) {
  int e = blockIdx.x * blockDim.x + threadIdx.x;
  if (e < E) atomicAdd(&cnt[dst[e]], 1);
}

__global__ __launch_bounds__(1024) void scanA_k(const int* __restrict__ cnt,
                                                int* __restrict__ rp,
                                                int* __restrict__ bsum, int n) {
  __shared__ int sh[1024];
  int i = blockIdx.x * 1024 + threadIdx.x;
  int v = (i < n) ? cnt[i] : 0;
  sh[threadIdx.x] = v;
  __syncthreads();
  for (int d = 1; d < 1024; d <<= 1) {
    int t = (threadIdx.x >= d) ? sh[threadIdx.x - d] : 0;
    __syncthreads();
    sh[threadIdx.x] += t;
    __syncthreads();
  }
  if (i < n) rp[i] = sh[threadIdx.x] - v;  // block-local exclusive
  if (threadIdx.x == 1023) bsum[blockIdx.x] = sh[1023];
}

__global__ void scanB_k(const int* __restrict__ bsum, int* __restrict__ boff, int nb) {
  if (blockIdx.x == 0 && threadIdx.x == 0) {
    int run = 0;
    for (int b = 0; b < nb; ++b) { boff[b] = run; run += bsum[b]; }
    boff[nb] = run;
  }
}

__global__ void scanC_k(int* __restrict__ rp, const int* __restrict__ boff, int n) {
  int i = blockIdx.x * blockDim.x + threadIdx.x;
  if (i < n) rp[i] += boff[i >> 10];
  if (i == 0) rp[n] = boff[(n + 1023) >> 10];
}

__global__ void scatter_k(const int* __restrict__ src, const int* __restrict__ dst,
                          const int* __restrict__ rp, int* __restrict__ cur,
                          int* __restrict__ out, int E) {
  int e = blockIdx.x * blockDim.x + threadIdx.x;
  if (e < E) {
    int d = dst[e];
    int p = rp[d] + atomicAdd(&cur[d], 1);
    out[p] = src[e];
  }
}

// ---------------- weight pre-split: W [K,Nc] fp32 -> Wh/Wl [256][K] bf16 ----------------
__global__ void convW1_k(const float* __restrict__ W, unsigned short* __restrict__ Wh,
                         unsigned short* __restrict__ Wl) {
  int id = blockIdx.x * 256 + threadIdx.x;  // 256*512
  int n = id >> 9, k = id & 511;
  unsigned h, l;
  split_bf16(W[k * 256 + n], h, l);
  Wh[id] = (unsigned short)h;
  Wl[id] = (unsigned short)l;
}

__global__ void convW2_k(const float* __restrict__ W, unsigned short* __restrict__ Wh,
                         unsigned short* __restrict__ Wl) {
  int id = blockIdx.x * 256 + threadIdx.x;  // 256*256, cols padded 160->256 per 64-group
  int n = id >> 8, k = id & 255;
  int hh = n >> 6, c = n & 63;
  float a = (c < OUTC) ? W[k * 160 + hh * OUTC + c] : 0.f;
  unsigned h, l;
  split_bf16(a, h, l);
  Wh[id] = (unsigned short)h;
  Wl[id] = (unsigned short)l;
}

// ---------------- m97-style DMA GEMM: C[M,256] = A[M,K] @ B[K,256] ----------------
// 128x128 tile, BK=32, 2-barrier K-loop, ALL staging via global_load_lds (no
// staging VGPRs -> no spill; R3-R5 showed VGPR-staged pipelines always spill).
// A_FP32: A is fp32 [M,K], staged raw to LDS, split to bf16 hi/lo at frag read.
// else:   A pre-split bf16 (Ah_/Al_) [M,K]. B always pre-split bf16 [n][K].
// COMPACT: store [M,160] (head-compact) instead of [M,256].
template <bool A_FP32, bool COMPACT>
__global__ __launch_bounds__(256) void gemm_dma(const void* Aptr_h, const void* Aptr_l,
                                                const unsigned short* __restrict__ Bh,
                                                const unsigned short* __restrict__ Bl,
                                                float* __restrict__ C, int M, int K) {
  __shared__ __align__(16) unsigned char lds_raw[32768];
  // layouts (unpadded rows -- DMA requires lane*16 contiguity, m104):
  //  A_FP32:  Af  [128][32] f32 @0 (16KB)
  //  !A_FP32: Ahs [128][32] bf16 @0 (8KB), Als @8192
  //  both:    Bhs [128][32] bf16 @16384, Bls @24576
  const int tid = threadIdx.x;
  const int lane = tid & 63;
  const int w = tid >> 6;
  const int wr = w >> 1, wc = w & 1;
  const int row0 = blockIdx.y * 128;
  const int col0 = blockIdx.x * 128;
  const int fr = lane & 15, fq = lane >> 4;

  floatx4 acc[4][4];
#pragma unroll
  for (int i = 0; i < 4; ++i)
#pragma unroll
    for (int j = 0; j < 4; ++j) acc[i][j] = (floatx4){0.f, 0.f, 0.f, 0.f};

  const float* Af32 = (const float*)Aptr_h;
  const unsigned short* Agh = (const unsigned short*)Aptr_h;
  const unsigned short* Agl = (const unsigned short*)Aptr_l;

  for (int k0 = 0; k0 < K; k0 += 32) {
    // ---- stage via DMA: 8 instrs/wave ----
    if (A_FP32) {
      // A tile 128x32 f32 = 16KB; 4 instrs/wave, 8 rows each (8 lanes/row)
#pragma unroll
      for (int t = 0; t < 4; ++t) {
        int arow = w * 32 + t * 8 + (lane >> 3);
        int gr = row0 + arow; gr = gr < M ? gr : M - 1;  // clamp: dup rows unused
        dma16(&Af32[(size_t)gr * K + k0 + (lane & 7) * 4],
              lds_raw + (size_t)(w * 32 + t * 8) * 128);
      }
    } else {
      // A hi/lo tiles 128x32 bf16 = 8KB each; 2 instrs/wave each (4 lanes/row)
#pragma unroll
      for (int t = 0; t < 2; ++t) {
        int arow = w * 32 + t * 16 + (lane >> 2);
        int gr = row0 + arow; gr = gr < M ? gr : M - 1;
        size_t go = (size_t)gr * K + k0 + (lane & 3) * 8;
        dma16(&Agh[go], lds_raw + (size_t)(w * 32 + t * 16) * 64);
        dma16(&Agl[go], lds_raw + 8192 + (size_t)(w * 32 + t * 16) * 64);
      }
    }
    // B hi/lo tiles 128x32 bf16; rows are output-cols (always in-bounds)
#pragma unroll
    for (int t = 0; t < 2; ++t) {
      int nrow = w * 32 + t * 16 + (lane >> 2);
      size_t go = (size_t)(col0 + nrow) * K + k0 + (lane & 3) * 8;
      dma16(&Bh[go], lds_raw + 16384 + (size_t)(w * 32 + t * 16) * 64);
      dma16(&Bl[go], lds_raw + 24576 + (size_t)(w * 32 + t * 16) * 64);
    }
    __syncthreads();  // drains vmcnt -> LDS tiles ready

    // ---- fragments ----
    bf16x8 ah[4], al[4], bh[4], bl[4];
#pragma unroll
    for (int i = 0; i < 4; ++i) {
      int arow = wr * 64 + i * 16 + fr;
      if (A_FP32) {
        const float* pr = (const float*)(lds_raw + (size_t)arow * 128 + fq * 32);
        float4 v0 = *(const float4*)pr;
        float4 v1 = *(const float4*)(pr + 4);
        unsigned u0 = __float_as_uint(v0.x), u1 = __float_as_uint(v0.y);
        unsigned u2 = __float_as_uint(v0.z), u3 = __float_as_uint(v0.w);
        unsigned u4 = __float_as_uint(v1.x), u5 = __float_as_uint(v1.y);
        unsigned u6 = __float_as_uint(v1.z), u7 = __float_as_uint(v1.w);
        uint4 H;
        H.x = (u0 >> 16) | (u1 & 0xFFFF0000u);
        H.y = (u2 >> 16) | (u3 & 0xFFFF0000u);
        H.z = (u4 >> 16) | (u5 & 0xFFFF0000u);
        H.w = (u6 >> 16) | (u7 & 0xFFFF0000u);
        uint4 L;
        L.x = (__float_as_uint(v0.x - __uint_as_float(u0 & 0xFFFF0000u)) >> 16) |
              (__float_as_uint(v0.y - __uint_as_float(u1 & 0xFFFF0000u)) & 0xFFFF0000u);
        L.y = (__float_as_uint(v0.z - __uint_as_float(u2 & 0xFFFF0000u)) >> 16) |
              (__float_as_uint(v0.w - __uint_as_float(u3 & 0xFFFF0000u)) & 0xFFFF0000u);
        L.z = (__float_as_uint(v1.x - __uint_as_float(u4 & 0xFFFF0000u)) >> 16) |
              (__float_as_uint(v1.y - __uint_as_float(u5 & 0xFFFF0000u)) & 0xFFFF0000u);
        L.w = (__float_as_uint(v1.z - __uint_as_float(u6 & 0xFFFF0000u)) >> 16) |
              (__float_as_uint(v1.w - __uint_as_float(u7 & 0xFFFF0000u)) & 0xFFFF0000u);
        ah[i] = *(bf16x8*)&H;
        al[i] = *(bf16x8*)&L;
      } else {
        ah[i] = *(bf16x8*)(lds_raw + (size_t)arow * 64 + fq * 16);
        al[i] = *(bf16x8*)(lds_raw + 8192 + (size_t)arow * 64 + fq * 16);
      }
      int brow = wc * 64 + i * 16 + fr;
      bh[i] = *(bf16x8*)(lds_raw + 16384 + (size_t)brow * 64 + fq * 16);
      bl[i] = *(bf16x8*)(lds_raw + 24576 + (size_t)brow * 64 + fq * 16);
    }
#pragma unroll
    for (int i = 0; i < 4; ++i)
#pragma unroll
      for (int j = 0; j < 4; ++j) {
        acc[i][j] = __builtin_amdgcn_mfma_f32_16x16x32_bf16(ah[i], bh[j], acc[i][j], 0, 0, 0);
        acc[i][j] = __builtin_amdgcn_mfma_f32_16x16x32_bf16(ah[i], bl[j], acc[i][j], 0, 0, 0);
        acc[i][j] = __builtin_amdgcn_mfma_f32_16x16x32_bf16(al[i], bh[j], acc[i][j], 0, 0, 0);
      }
    __syncthreads();  // all frag reads done before next iter's DMA overwrites
  }

  // epilogue: C/D layout col=lane&15, row=(lane>>4)*4+r  [m89]
#pragma unroll
  for (int i = 0; i < 4; ++i) {
    int grow_base = row0 + wr * 64 + i * 16 + fq * 4;
#pragma unroll
    for (int r = 0; r < 4; ++r) {
      int grow = grow_base + r;
      if (grow < M) {
        if (COMPACT) {
          int head = blockIdx.x * 2 + wc;
#pragma unroll
          for (int j = 0; j < 4; ++j) {
            int cc = j * 16 + fr;
            if (cc < OUTC) C[(size_t)grow * 160 + head * OUTC + cc] = acc[i][j][r];
          }
        } else {
#pragma unroll
          for (int j = 0; j < 4; ++j)
            C[(size_t)grow * 256 + col0 + wc * 64 + j * 16 + fr] = acc[i][j][r];
        }
      }
    }
  }
}

// ---------------- layer-1 agg: wave per node; emits pre-split bf16 activations ----
__global__ __launch_bounds__(256) void agg1_k(const float* __restrict__ h,
                                              const int* __restrict__ rp,
                                              const int* __restrict__ srt,
                                              const float* __restrict__ b1,
                                              unsigned short* __restrict__ outh,
                                              unsigned short* __restrict__ outl, int Nn) {
  int wv = threadIdx.x >> 6, lane = threadIdx.x & 63;
  int node = blockIdx.x * 4 + wv;
  if (node >= Nn) node = Nn - 1;
  const float4 xi = *(const float4*)&h[(size_t)node * 256 + lane * 4];
  float p = xi.x * xi.x + xi.y * xi.y + xi.z * xi.z + xi.w * xi.w;
  p += __shfl_xor(p, 1); p += __shfl_xor(p, 2); p += __shfl_xor(p, 4); p += __shfl_xor(p, 8);
  float a = p > 0.f ? p : NEG * p;      // self-loop logit
  float m = a, l = 1.f;
  float4 acc = xi;
  const int e0 = rp[node], e1 = rp[node + 1];
  for (int e = e0; e < e1; ++e) {
    int s = srt[e];
    const float4 xj = *(const float4*)&h[(size_t)s * 256 + lane * 4];
    float q = xi.x * xj.x + xi.y * xj.y + xi.z * xj.z + xi.w * xj.w;
    q += __shfl_xor(q, 1); q += __shfl_xor(q, 2); q += __shfl_xor(q, 4); q += __shfl_xor(q, 8);
    float al = q > 0.f ? q : NEG * q;
    float nm = fmaxf(m, al);
    float sc = __expf(m - nm), wt = __expf(al - nm);
    l = l * sc + wt;
    acc.x = acc.x * sc + wt * xj.x;
    acc.y = acc.y * sc + wt * xj.y;
    acc.z = acc.z * sc + wt * xj.z;
    acc.w = acc.w * sc + wt * xj.w;
    m = nm;
  }
  float inv = 1.f / (l + EPSV);
  const float4 bb = *(const float4*)&b1[lane * 4];
  float4 o;
  o.x = acc.x * inv + bb.x;
  o.y = acc.y * inv + bb.y;
  o.z = acc.z * inv + bb.z;
  o.w = acc.w * inv + bb.w;
  o.x = o.x > 0.f ? o.x : __expf(o.x) - 1.f;
  o.y = o.y > 0.f ? o.y : __expf(o.y) - 1.f;
  o.z = o.z > 0.f ? o.z : __expf(o.z) - 1.f;
  o.w = o.w > 0.f ? o.w : __expf(o.w) - 1.f;
  unsigned h0, l0, h1, l1, h2, l2, h3, l3;
  split_bf16(o.x, h0, l0);
  split_bf16(o.y, h1, l1);
  split_bf16(o.z, h2, l2);
  split_bf16(o.w, h3, l3);
  size_t base = (size_t)node * 256 + lane * 4;
  *(uint2*)&outh[base] = make_uint2(h0 | (h1 << 16), h2 | (h3 << 16));
  *(uint2*)&outl[base] = make_uint2(l0 | (l1 << 16), l2 | (l3 << 16));
}

// ---------------- layer-2 agg (compact [N,160] input) + head-mean + log_softmax ----------------
__global__ __launch_bounds__(256) void agg2_k(const float* __restrict__ h,
                                              const int* __restrict__ rp,
                                              const int* __restrict__ srt,
                                              const float* __restrict__ b2,
                                              float* __restrict__ out, int Nn) {
  __shared__ float buf[4][160];
  int wv = threadIdx.x >> 6, lane = threadIdx.x & 63;
  int node = blockIdx.x * 4 + wv;
  if (node >= Nn) node = Nn - 1;
  const int head = lane >> 4, c4 = lane & 15;
  const bool act = c4 < 10;  // 10 lanes x float4 = 40 channels per head
  float4 xi = make_float4(0.f, 0.f, 0.f, 0.f);
  if (act) xi = *(const float4*)&h[(size_t)node * 160 + head * OUTC + c4 * 4];
  float p = xi.x * xi.x + xi.y * xi.y + xi.z * xi.z + xi.w * xi.w;
  p += __shfl_xor(p, 1); p += __shfl_xor(p, 2); p += __shfl_xor(p, 4); p += __shfl_xor(p, 8);
  float a = p > 0.f ? p : NEG * p;
  float m = a, l = 1.f;
  float4 acc = xi;
  const int e0 = rp[node], e1 = rp[node + 1];
  for (int e = e0; e < e1; ++e) {
    int s = srt[e];
    float4 xj = make_float4(0.f, 0.f, 0.f, 0.f);
    if (act) xj = *(const float4*)&h[(size_t)s * 160 + head * OUTC + c4 * 4];
    float q = xi.x * xj.x + xi.y * xj.y + xi.z * xj.z + xi.w * xj.w;
    q += __shfl_xor(q, 1); q += __shfl_xor(q, 2); q += __shfl_xor(q, 4); q += __shfl_xor(q, 8);
    float al = q > 0.f ? q : NEG * q;
    float nm = fmaxf(m, al);
    float sc = __expf(m - nm), wt = __expf(al - nm);
    l = l * sc + wt;
    acc.x = acc.x * sc + wt * xj.x;
    acc.y = acc.y * sc + wt * xj.y;
    acc.z = acc.z * sc + wt * xj.z;
    acc.w = acc.w * sc + wt * xj.w;
    m = nm;
  }
  float inv = 1.f / (l + EPSV);
  if (act) {
    float4 res;
    res.x = acc.x * inv; res.y = acc.y * inv; res.z = acc.z * inv; res.w = acc.w * inv;
    *(float4*)&buf[wv][head * OUTC + c4 * 4] = res;
  }
  __syncthreads();
  const bool valid = lane < OUTC;
  float v = 0.f;
  if (valid)
    v = 0.25f * (buf[wv][lane] + buf[wv][OUTC + lane] + buf[wv][2 * OUTC + lane] +
                 buf[wv][3 * OUTC + lane]) + b2[lane];
  float t = valid ? v : -1e30f;
#pragma unroll
  for (int off = 32; off; off >>= 1) t = fmaxf(t, __shfl_xor(t, off));
  float ex = valid ? __expf(v - t) : 0.f;
  float s = ex;
#pragma unroll
  for (int off = 32; off; off >>= 1) s += __shfl_xor(s, off);
  float lse = t + __logf(s);
  if (valid) out[(size_t)node * OUTC + lane] = v - lse;
  if (blockIdx.x == 0 && threadIdx.x == 0) out[(size_t)Nn * OUTC] = 0.f;  // att_loss
}

extern "C" void kernel_launch(void* const* d_in, const int* in_sizes, int n_in,
                              void* d_out, int out_size, void* d_ws, size_t ws_size,
                              hipStream_t stream) {
  const float* x  = (const float*)d_in[0];
  const int*   ei = (const int*)d_in[1];
  const float* W1 = (const float*)d_in[2];
  const float* b1 = (const float*)d_in[3];
  const float* W2 = (const float*)d_in[4];
  const float* b2 = (const float*)d_in[5];
  float* out = (float*)d_out;

  const int Nn = in_sizes[0] / 512;  // 50000
  const int E  = in_sizes[1] / 2;    // 400000
  const int* esrc = ei;
  const int* edst = ei + E;
  const int NB = (Nn + 1023) / 1024;

  // workspace layout
  char* ws = (char*)d_ws;
  const size_t szH = (size_t)Nn * 256 * sizeof(float);  // 51.2 MB
  float* h1 = (float*)(ws);           // GEMM1 out [N,256] f32; reused as h2 [N,160] f32
  size_t off = szH;
  unsigned short* g1h = (unsigned short*)(ws + off); off += (size_t)Nn * 256 * 2;  // 25.6MB
  unsigned short* g1l = (unsigned short*)(ws + off); off += (size_t)Nn * 256 * 2;
  int* rp = (int*)(ws + off);   off += ((size_t)(Nn + 1) * 4 + 15) & ~(size_t)15;
  int* cnt = (int*)(ws + off);  off += ((size_t)Nn * 4 + 15) & ~(size_t)15;
  int* srt = (int*)(ws + off);  off += ((size_t)E * 4 + 15) & ~(size_t)15;
  int* bsum = (int*)(ws + off); off += 1024;
  int* boff = (int*)(ws + off); off += 1024;
  unsigned short* Wh1 = (unsigned short*)(ws + off); off += (size_t)256 * 512 * 2;
  unsigned short* Wl1 = (unsigned short*)(ws + off); off += (size_t)256 * 512 * 2;
  unsigned short* Wh2 = (unsigned short*)(ws + off); off += (size_t)256 * 256 * 2;
  unsigned short* Wl2 = (unsigned short*)(ws + off); off += (size_t)256 * 256 * 2;
  float* h2 = h1;

  // CSR by destination
  hipMemsetAsync(cnt, 0, (size_t)Nn * sizeof(int), stream);
  hist_k<<<(E + 255) / 256, 256, 0, stream>>>(edst, cnt, E);
  scanA_k<<<NB, 1024, 0, stream>>>(cnt, rp, bsum, Nn);
  scanB_k<<<1, 64, 0, stream>>>(bsum, boff, NB);
  scanC_k<<<(Nn + 255) / 256, 256, 0, stream>>>(rp, boff, Nn);
  hipMemsetAsync(cnt, 0, (size_t)Nn * sizeof(int), stream);
  scatter_k<<<(E + 255) / 256, 256, 0, stream>>>(esrc, edst, rp, cnt, srt, E);

  // weight pre-split
  convW1_k<<<512, 256, 0, stream>>>(W1, Wh1, Wl1);
  convW2_k<<<256, 256, 0, stream>>>(W2, Wh2, Wl2);

  // layer 1: A = x fp32 (read-time split), B = Wh1/Wl1
  gemm_dma<true, false>
      <<<dim3(2, (Nn + 127) / 128), 256, 0, stream>>>(x, nullptr, Wh1, Wl1, h1, Nn, 512);
  agg1_k<<<(Nn + 3) / 4, 256, 0, stream>>>(h1, rp, srt, b1, g1h, g1l, Nn);

  // layer 2: A = g1 pre-split bf16, compact [N,160] output
  gemm_dma<false, true>
      <<<dim3(2, (Nn + 127) / 128), 256, 0, stream>>>(g1h, g1l, Wh2, Wl2, h2, Nn, 256);
  agg2_k<<<(Nn + 3) / 4, 256, 0, stream>>>(h2, rp, srt, b2, out, Nn);
}